// Round 3
// baseline (133.941 us; speedup 1.0000x reference)
//
#include <hip/hip_runtime.h>

// LSNet collapse: final mask x == 0 everywhere (argmax over identical negsum9
// channels == 0), so the network reduces to:
//   c2  = sum(inp) / 4194304
//   out = tanh( c2^2 * sum_inbounds(w) - 2*c2 * conv3x3x3(inp, w) )   (zero pad)
// with w = c1_w (27 taps). Biases cancel exactly.

#define NVOX (2 * 128 * 128 * 128)   // 4194304

__global__ __launch_bounds__(256) void k_reduce_partial(const float* __restrict__ inp,
                                                        float* __restrict__ partial) {
    // 1024 blocks x 256 threads; each thread sums 4 float4 (16 floats)
    int tid = blockIdx.x * 256 + threadIdx.x;           // 0 .. 262143
    const float4* in4 = (const float4*)inp;
    float s = 0.f;
#pragma unroll
    for (int i = 0; i < 4; ++i) {
        float4 v = in4[tid + i * 262144];
        s += (v.x + v.y) + (v.z + v.w);
    }
#pragma unroll
    for (int off = 32; off > 0; off >>= 1) s += __shfl_down(s, off, 64);
    __shared__ float ws[4];
    int lane = threadIdx.x & 63;
    int wid  = threadIdx.x >> 6;
    if (lane == 0) ws[wid] = s;
    __syncthreads();
    if (threadIdx.x == 0) partial[blockIdx.x] = (ws[0] + ws[1]) + (ws[2] + ws[3]);
}

__global__ __launch_bounds__(1024) void k_reduce_final(const float* __restrict__ partial,
                                                       float* __restrict__ c2out) {
    float s = partial[threadIdx.x];
#pragma unroll
    for (int off = 32; off > 0; off >>= 1) s += __shfl_down(s, off, 64);
    __shared__ float ws[16];
    int lane = threadIdx.x & 63;
    int wid  = threadIdx.x >> 6;
    if (lane == 0) ws[wid] = s;
    __syncthreads();
    if (threadIdx.x == 0) {
        float t = 0.f;
#pragma unroll
        for (int i = 0; i < 16; ++i) t += ws[i];
        // reference: sum(inp*1) / (sum(1) + 1e-8); in fp32 4194304 + 1e-8 == 4194304
        *c2out = t / (float)NVOX;
    }
}

__global__ __launch_bounds__(512) void k_stencil(const float* __restrict__ inp,
                                                 const float* __restrict__ w27,
                                                 const float* __restrict__ c2ptr,
                                                 float* __restrict__ out) {
    const float c2 = *c2ptr;

    // 27 taps -> registers (uniform scalar loads)
    float wr[27];
#pragma unroll
    for (int i = 0; i < 27; ++i) wr[i] = w27[i];

    int w  = threadIdx.x;                        // 0..127
    int h  = blockIdx.y * 4 + threadIdx.y;       // 0..127
    int nd = blockIdx.z;                         // n*128 + d, 0..255
    int d  = nd & 127;

    float acc  = 0.f;   // sum w*inp over in-bounds taps
    float wsum = 0.f;   // sum w over in-bounds taps
#pragma unroll
    for (int dz = -1; dz <= 1; ++dz) {
        int d2 = d + dz;
        if ((unsigned)d2 >= 128u) continue;
#pragma unroll
        for (int dy = -1; dy <= 1; ++dy) {
            int h2 = h + dy;
            if ((unsigned)h2 >= 128u) continue;
            const float* row = inp + ((size_t)(nd + dz) << 14) + (h2 << 7);
#pragma unroll
            for (int dx = -1; dx <= 1; ++dx) {
                int w2 = w + dx;
                if ((unsigned)w2 >= 128u) continue;
                float wt = wr[(dz + 1) * 9 + (dy + 1) * 3 + (dx + 1)];
                acc  = fmaf(wt, row[w2], acc);
                wsum += wt;
            }
        }
    }
    float val = c2 * c2 * wsum - 2.f * c2 * acc;
    out[((size_t)nd << 14) + (h << 7) + w] = tanhf(val);
}

extern "C" void kernel_launch(void* const* d_in, const int* in_sizes, int n_in,
                              void* d_out, int out_size, void* d_ws, size_t ws_size,
                              hipStream_t stream) {
    // inputs (setup_inputs order): 0=x, 1=inp, 2=conv_w, 3=conv_b, 4=bn_g,
    //                              5=bn_b, 6=c1_w, 7=c1_b
    const float* inp = (const float*)d_in[1];
    const float* c1w = (const float*)d_in[6];
    float* out = (float*)d_out;

    float* ws      = (float*)d_ws;
    float* partial = ws;          // 1024 floats
    float* c2p     = ws + 1024;   // 1 float

    hipLaunchKernelGGL(k_reduce_partial, dim3(1024), dim3(256), 0, stream, inp, partial);
    hipLaunchKernelGGL(k_reduce_final, dim3(1), dim3(1024), 0, stream, partial, c2p);

    dim3 blk(128, 4, 1);
    dim3 grd(1, 32, 256);   // y: 32 h-tiles of 4, z: n*d = 256
    hipLaunchKernelGGL(k_stencil, grd, blk, 0, stream, inp, c1w, c2p, out);
}

// Round 4
// 102.020 us; speedup vs baseline: 1.3129x; 1.3129x over previous
//
#include <hip/hip_runtime.h>

// LSNet collapse: final mask x == 0 everywhere (argmax over identical negsum9
// channels == 0), so the network reduces to:
//   c2  = sum(inp) / 4194304
//   out = tanh( conv3x3x3( c2^2 - 2*c2*inp , c1_w, zero-pad-excluded ) )
// (out-of-bounds taps contribute 0 exactly, since the reference convolves
//  (inp-c2)^2 and inp^2 with zero padding and the biases cancel).

#define NVOX (2 * 128 * 128 * 128)   // 4194304

__global__ __launch_bounds__(256) void k_reduce_partial(const float* __restrict__ inp,
                                                        float* __restrict__ partial) {
    // 1024 blocks x 256 threads; each thread sums 4 float4 (16 floats)
    int tid = blockIdx.x * 256 + threadIdx.x;           // 0 .. 262143
    const float4* in4 = (const float4*)inp;
    float s = 0.f;
#pragma unroll
    for (int i = 0; i < 4; ++i) {
        float4 v = in4[tid + i * 262144];
        s += (v.x + v.y) + (v.z + v.w);
    }
#pragma unroll
    for (int off = 32; off > 0; off >>= 1) s += __shfl_down(s, off, 64);
    __shared__ float ws[4];
    int lane = threadIdx.x & 63;
    int wid  = threadIdx.x >> 6;
    if (lane == 0) ws[wid] = s;
    __syncthreads();
    if (threadIdx.x == 0) partial[blockIdx.x] = (ws[0] + ws[1]) + (ws[2] + ws[3]);
}

// block = (32, 8): tx = x-quad (4 floats each -> full 128 x), ty = h row.
// grid = (1, 16, 256): 16 h-tiles of 8, z = n*128 + d.
__global__ __launch_bounds__(256) void k_stencil(const float* __restrict__ inp,
                                                 const float* __restrict__ w27,
                                                 const float* __restrict__ partial,
                                                 float* __restrict__ out) {
    const int tx  = threadIdx.x;                  // 0..31
    const int ty  = threadIdx.y;                  // 0..7
    const int lin = ty * 32 + tx;                 // 0..255
    const int lane = lin & 63;

    // ---- fold the final reduction: sum 1024 partials (4 KB, L2-hot) ----
    __shared__ float ws[4];
    __shared__ float c2sh;
    {
        const float4* p4 = (const float4*)partial;   // 256 float4
        float4 v = p4[lin];
        float s = (v.x + v.y) + (v.z + v.w);
#pragma unroll
        for (int off = 32; off > 0; off >>= 1) s += __shfl_down(s, off, 64);
        if (lane == 0) ws[lin >> 6] = s;
        __syncthreads();
        if (lin == 0) c2sh = ((ws[0] + ws[1]) + (ws[2] + ws[3])) / (float)NVOX;
        __syncthreads();
    }
    const float c2   = c2sh;
    const float c2sq = c2 * c2;
    const float m2c2 = -2.f * c2;

    // 27 taps (uniform address -> scalar loads)
    float wr[27];
#pragma unroll
    for (int i = 0; i < 27; ++i) wr[i] = w27[i];

    const int h  = blockIdx.y * 8 + ty;           // 0..127
    const int nd = blockIdx.z;                    // n*128 + d
    const int d  = nd & 127;

    float4 acc = {0.f, 0.f, 0.f, 0.f};

#pragma unroll
    for (int dz = -1; dz <= 1; ++dz) {
        int d2 = d + dz;
        if ((unsigned)d2 >= 128u) continue;
#pragma unroll
        for (int dy = -1; dy <= 1; ++dy) {
            int h2 = h + dy;
            if ((unsigned)h2 >= 128u) continue;
            const float4* row = (const float4*)(inp + ((size_t)(nd + dz) << 14) + (h2 << 7));
            float4 v = row[tx];
            // transform: t = c2^2 - 2*c2*x  (== (x-c2)^2 - x^2)
            float4 t;
            t.x = fmaf(m2c2, v.x, c2sq);
            t.y = fmaf(m2c2, v.y, c2sq);
            t.z = fmaf(m2c2, v.z, c2sq);
            t.w = fmaf(m2c2, v.w, c2sq);
            // x-neighbors from adjacent lanes (same h row: tx 0..31 within lane group)
            float tL = __shfl(t.w, (lane - 1) & 63, 64);
            float tR = __shfl(t.x, (lane + 1) & 63, 64);
            if (tx == 0)  tL = 0.f;   // x pad: tap contributes 0
            if (tx == 31) tR = 0.f;
            const int r = (dz + 1) * 9 + (dy + 1) * 3;
            const float w0 = wr[r], w1 = wr[r + 1], w2 = wr[r + 2];
            acc.x = fmaf(w0, tL,  fmaf(w1, t.x, fmaf(w2, t.y, acc.x)));
            acc.y = fmaf(w0, t.x, fmaf(w1, t.y, fmaf(w2, t.z, acc.y)));
            acc.z = fmaf(w0, t.y, fmaf(w1, t.z, fmaf(w2, t.w, acc.z)));
            acc.w = fmaf(w0, t.z, fmaf(w1, t.w, fmaf(w2, tR,  acc.w)));
        }
    }

    float4 o;
    o.x = tanhf(acc.x);
    o.y = tanhf(acc.y);
    o.z = tanhf(acc.z);
    o.w = tanhf(acc.w);
    float4* out4 = (float4*)(out + ((size_t)nd << 14) + (h << 7));
    out4[tx] = o;
}

extern "C" void kernel_launch(void* const* d_in, const int* in_sizes, int n_in,
                              void* d_out, int out_size, void* d_ws, size_t ws_size,
                              hipStream_t stream) {
    // inputs (setup_inputs order): 0=x, 1=inp, 2=conv_w, 3=conv_b, 4=bn_g,
    //                              5=bn_b, 6=c1_w, 7=c1_b
    const float* inp = (const float*)d_in[1];
    const float* c1w = (const float*)d_in[6];
    float* out = (float*)d_out;

    float* partial = (float*)d_ws;   // 1024 floats

    hipLaunchKernelGGL(k_reduce_partial, dim3(1024), dim3(256), 0, stream, inp, partial);

    dim3 blk(32, 8, 1);
    dim3 grd(1, 16, 256);
    hipLaunchKernelGGL(k_stencil, grd, blk, 0, stream, inp, c1w, partial, out);
}